// Round 2
// baseline (845.230 us; speedup 1.0000x reference)
//
#include <hip/hip_runtime.h>
#include <hip/hip_bf16.h>

typedef __hip_bfloat16 bf16;

#define Bn 8
#define Cn 256
#define Hn 64
#define Wn 64
#define Nn 4096          // H*W
#define Mn 1024          // pooled
#define EPSf 1e-5f

__device__ __forceinline__ float b2f(const bf16 v){ return __bfloat162float(v); }

// ---------------- theta: Q[b][n][64] = theta_w(64x64) @ x[b][0:64][n] + theta_b
// grid (32, B): hr = row-pair (2 rows = 128 positions). block 256.
__global__ __launch_bounds__(256) void theta_kernel(
    const float* __restrict__ x, const float* __restrict__ tw, const float* __restrict__ tb,
    bf16* __restrict__ Q)
{
  __shared__ float xs[64][130];
  __shared__ float ws[64][65];
  const int t = threadIdx.x;
  const int hr = blockIdx.x, b = blockIdx.y;
  const long xbase = ((long)b*Cn)*Nn + hr*128;
  for (int i = 0; i < 32; ++i) {
    int idx = t + i*256; int c = idx >> 7, p = idx & 127;
    xs[c][p] = x[xbase + (long)c*Nn + p];
  }
  for (int i = 0; i < 16; ++i) {
    int idx = t + i*256; int o = idx >> 6, c = idx & 63;
    ws[o][c] = tw[o*64 + c];
  }
  __syncthreads();
  const int oq = t >> 4, pq = t & 15;
  int pp[8];
  #pragma unroll
  for (int j = 0; j < 8; ++j) pp[j] = pq*8 + ((j + pq + (pq>>2)) & 7);
  float acc[4][8];
  #pragma unroll
  for (int i = 0; i < 4; ++i)
    #pragma unroll
    for (int j = 0; j < 8; ++j) acc[i][j] = 0.f;
  for (int c = 0; c < 64; ++c) {
    float wv[4], xv[8];
    #pragma unroll
    for (int i = 0; i < 4; ++i) wv[i] = ws[oq*4+i][c];
    #pragma unroll
    for (int j = 0; j < 8; ++j) xv[j] = xs[c][pp[j]];
    #pragma unroll
    for (int i = 0; i < 4; ++i)
      #pragma unroll
      for (int j = 0; j < 8; ++j) acc[i][j] += wv[i]*xv[j];
  }
  __syncthreads();
  #pragma unroll
  for (int i = 0; i < 4; ++i) {
    float bias = tb[oq*4+i];
    #pragma unroll
    for (int j = 0; j < 8; ++j) xs[oq*4+i][pp[j]] = acc[i][j] + bias;
  }
  __syncthreads();
  const int o = t & 63, g = t >> 6;
  const long qbase = ((long)b*Nn + hr*128)*64;
  for (int i = 0; i < 32; ++i) {
    int p = g*32 + i;
    Q[qbase + (long)p*64 + o] = __float2bfloat16(xs[o][p]);
  }
}

// ---------------- phi: K[b][m][64] = maxpool2(phi_w(64x192) @ x[b][64:256] + phi_b)
// grid (32, B): hp = pooled row. block 256.
__global__ __launch_bounds__(256) void phi_kernel(
    const float* __restrict__ x, const float* __restrict__ pw, const float* __restrict__ pb,
    bf16* __restrict__ K)
{
  __shared__ float xs[64][130];
  __shared__ float ws[64][65];
  const int t = threadIdx.x;
  const int hp = blockIdx.x, b = blockIdx.y;
  const int oq = t >> 4, pq = t & 15;
  int pp[8];
  #pragma unroll
  for (int j = 0; j < 8; ++j) pp[j] = pq*8 + ((j + pq + (pq>>2)) & 7);
  float acc[4][8];
  #pragma unroll
  for (int i = 0; i < 4; ++i)
    #pragma unroll
    for (int j = 0; j < 8; ++j) acc[i][j] = 0.f;
  for (int ch = 0; ch < 3; ++ch) {
    __syncthreads();
    const long xbase = ((long)b*Cn + 64 + ch*64)*Nn + hp*128;
    for (int i = 0; i < 32; ++i) {
      int idx = t + i*256; int c = idx >> 7, p = idx & 127;
      xs[c][p] = x[xbase + (long)c*Nn + p];
    }
    for (int i = 0; i < 16; ++i) {
      int idx = t + i*256; int o = idx >> 6, c = idx & 63;
      ws[o][c] = pw[o*192 + ch*64 + c];
    }
    __syncthreads();
    for (int c = 0; c < 64; ++c) {
      float wv[4], xv[8];
      #pragma unroll
      for (int i = 0; i < 4; ++i) wv[i] = ws[oq*4+i][c];
      #pragma unroll
      for (int j = 0; j < 8; ++j) xv[j] = xs[c][pp[j]];
      #pragma unroll
      for (int i = 0; i < 4; ++i)
        #pragma unroll
        for (int j = 0; j < 8; ++j) acc[i][j] += wv[i]*xv[j];
    }
  }
  __syncthreads();
  #pragma unroll
  for (int i = 0; i < 4; ++i) {
    float bias = pb[oq*4+i];
    #pragma unroll
    for (int j = 0; j < 8; ++j) xs[oq*4+i][pp[j]] = acc[i][j] + bias;
  }
  __syncthreads();
  const int o = t & 63, wq = t >> 6;
  for (int i = 0; i < 8; ++i) {
    int wp = wq*8 + i;
    float v = fmaxf(fmaxf(xs[o][2*wp], xs[o][2*wp+1]),
                    fmaxf(xs[o][64+2*wp], xs[o][64+2*wp+1]));
    K[((long)b*Mn + hp*32 + wp)*64 + o] = __float2bfloat16(v);
  }
}

// ---------------- g: V[b][m][256] = maxpool2(g_w(256x256) @ x[b][:] + g_b)
// grid (32, 4, B): hp, o-chunk, b. block 256.
__global__ __launch_bounds__(256) void g_kernel(
    const float* __restrict__ x, const float* __restrict__ gw, const float* __restrict__ gb,
    bf16* __restrict__ V)
{
  __shared__ float xs[64][130];
  __shared__ float ws[64][65];
  const int t = threadIdx.x;
  const int hp = blockIdx.x, o0 = blockIdx.y*64, b = blockIdx.z;
  const int oq = t >> 4, pq = t & 15;
  int pp[8];
  #pragma unroll
  for (int j = 0; j < 8; ++j) pp[j] = pq*8 + ((j + pq + (pq>>2)) & 7);
  float acc[4][8];
  #pragma unroll
  for (int i = 0; i < 4; ++i)
    #pragma unroll
    for (int j = 0; j < 8; ++j) acc[i][j] = 0.f;
  for (int ch = 0; ch < 4; ++ch) {
    __syncthreads();
    const long xbase = ((long)b*Cn + ch*64)*Nn + hp*128;
    for (int i = 0; i < 32; ++i) {
      int idx = t + i*256; int c = idx >> 7, p = idx & 127;
      xs[c][p] = x[xbase + (long)c*Nn + p];
    }
    for (int i = 0; i < 16; ++i) {
      int idx = t + i*256; int o = idx >> 6, c = idx & 63;
      ws[o][c] = gw[(o0 + o)*256 + ch*64 + c];
    }
    __syncthreads();
    for (int c = 0; c < 64; ++c) {
      float wv[4], xv[8];
      #pragma unroll
      for (int i = 0; i < 4; ++i) wv[i] = ws[oq*4+i][c];
      #pragma unroll
      for (int j = 0; j < 8; ++j) xv[j] = xs[c][pp[j]];
      #pragma unroll
      for (int i = 0; i < 4; ++i)
        #pragma unroll
        for (int j = 0; j < 8; ++j) acc[i][j] += wv[i]*xv[j];
    }
  }
  __syncthreads();
  #pragma unroll
  for (int i = 0; i < 4; ++i) {
    float bias = gb[o0 + oq*4+i];
    #pragma unroll
    for (int j = 0; j < 8; ++j) xs[oq*4+i][pp[j]] = acc[i][j] + bias;
  }
  __syncthreads();
  const int o = t & 63, wq = t >> 6;
  for (int i = 0; i < 8; ++i) {
    int wp = wq*8 + i;
    float v = fmaxf(fmaxf(xs[o][2*wp], xs[o][2*wp+1]),
                    fmaxf(xs[o][64+2*wp], xs[o][64+2*wp+1]));
    V[((long)b*Mn + hp*32 + wp)*256 + o0 + o] = __float2bfloat16(v);
  }
}

// ---------------- flash attention: Y[b][n][256]
// grid (128, B): 32-row Q tiles; loop 32-col m tiles with online softmax.
__global__ __launch_bounds__(256) void attn_kernel(
    const bf16* __restrict__ Q, const bf16* __restrict__ K, const bf16* __restrict__ V,
    bf16* __restrict__ Y)
{
  __shared__ float Qs[32][65];
  __shared__ float Ks[32][65];
  __shared__ float Vs[32][256];
  __shared__ float Ss[32][33];
  __shared__ float m_sh[32], l_sh[32], a_sh[32];
  const int t = threadIdx.x;
  const int q0 = blockIdx.x*32, b = blockIdx.y;
  for (int i = 0; i < 8; ++i) {
    int idx = t + i*256; int r = idx >> 6, c = idx & 63;
    Qs[r][c] = b2f(Q[((long)b*Nn + q0 + r)*64 + c]);
  }
  if (t < 32) { m_sh[t] = -3e38f; l_sh[t] = 0.f; }
  const int rq = t >> 4, cq = t & 15;   // 2x2 score tile
  const int rg = t >> 5, cg = t & 31;   // 4 rows x 8 strided cols for PV
  float acc[4][8];
  #pragma unroll
  for (int i = 0; i < 4; ++i)
    #pragma unroll
    for (int k = 0; k < 8; ++k) acc[i][k] = 0.f;
  for (int mt = 0; mt < 32; ++mt) {
    const int m0 = mt*32;
    __syncthreads();
    for (int i = 0; i < 8; ++i) {
      int idx = t + i*256; int r = idx >> 6, c = idx & 63;
      Ks[r][c] = b2f(K[((long)b*Mn + m0 + r)*64 + c]);
    }
    for (int i = 0; i < 32; ++i) {
      int idx = t + i*256; int j = idx >> 8, c = idx & 255;
      Vs[j][c] = b2f(V[((long)b*Mn + m0 + j)*256 + c]);
    }
    __syncthreads();
    float s00=0.f, s01=0.f, s10=0.f, s11=0.f;
    for (int c = 0; c < 64; ++c) {
      float qa = Qs[rq*2][c], qb = Qs[rq*2+1][c];
      float ka = Ks[cq*2][c], kb = Ks[cq*2+1][c];
      s00 += qa*ka; s01 += qa*kb; s10 += qb*ka; s11 += qb*kb;
    }
    Ss[rq*2][cq*2]   = s00; Ss[rq*2][cq*2+1]   = s01;
    Ss[rq*2+1][cq*2] = s10; Ss[rq*2+1][cq*2+1] = s11;
    __syncthreads();
    if (t < 32) {
      float mo = m_sh[t], mx = mo;
      for (int j = 0; j < 32; ++j) mx = fmaxf(mx, Ss[t][j]);
      float al = __expf(mo - mx);
      float sum = 0.f;
      for (int j = 0; j < 32; ++j) {
        float p = __expf(Ss[t][j] - mx);
        Ss[t][j] = p; sum += p;
      }
      m_sh[t] = mx; l_sh[t] = l_sh[t]*al + sum; a_sh[t] = al;
    }
    __syncthreads();
    float av[4];
    #pragma unroll
    for (int ii = 0; ii < 4; ++ii) av[ii] = a_sh[rg*4+ii];
    #pragma unroll
    for (int ii = 0; ii < 4; ++ii)
      #pragma unroll
      for (int k = 0; k < 8; ++k) acc[ii][k] *= av[ii];
    for (int j = 0; j < 32; ++j) {
      float pv[4];
      #pragma unroll
      for (int ii = 0; ii < 4; ++ii) pv[ii] = Ss[rg*4+ii][j];
      #pragma unroll
      for (int k = 0; k < 8; ++k) {
        float vv = Vs[j][cg + 32*k];
        #pragma unroll
        for (int ii = 0; ii < 4; ++ii) acc[ii][k] += pv[ii]*vv;
      }
    }
  }
  #pragma unroll
  for (int ii = 0; ii < 4; ++ii) {
    int r = rg*4 + ii;
    float inv = 1.f / l_sh[r];
    #pragma unroll
    for (int k = 0; k < 8; ++k)
      Y[((long)b*Nn + q0 + r)*256 + cg + 32*k] = __float2bfloat16(acc[ii][k]*inv);
  }
}

// ---------------- W conv + BN + residual
// grid (64, 4, B): n-tile 64, o-chunk 64, b. block 256.
__global__ __launch_bounds__(256) void wconv_kernel(
    const bf16* __restrict__ Y, const float* __restrict__ Ww, const float* __restrict__ Wb,
    const float* __restrict__ gamma, const float* __restrict__ beta,
    const float* __restrict__ mean, const float* __restrict__ var,
    const float* __restrict__ x, float* __restrict__ out)
{
  __shared__ float ys[64][65];
  __shared__ float ws[64][65];
  __shared__ float ssc[64], ssh[64];
  const int t = threadIdx.x;
  const int n0 = blockIdx.x*64, o0 = blockIdx.y*64, b = blockIdx.z;
  if (t < 64) {
    int o = o0 + t;
    float sc = gamma[o] * rsqrtf(var[o] + EPSf);
    ssc[t] = sc;
    ssh[t] = (Wb[o] - mean[o])*sc + beta[o];
  }
  const int oq = t >> 4, nq = t & 15;
  float acc[4][4];
  #pragma unroll
  for (int i = 0; i < 4; ++i)
    #pragma unroll
    for (int j = 0; j < 4; ++j) acc[i][j] = 0.f;
  for (int ch = 0; ch < 4; ++ch) {
    __syncthreads();
    for (int i = 0; i < 16; ++i) {
      int idx = t + i*256; int n = idx >> 6, c = idx & 63;
      ys[n][c] = b2f(Y[((long)b*Nn + n0 + n)*256 + ch*64 + c]);
    }
    for (int i = 0; i < 16; ++i) {
      int idx = t + i*256; int o = idx >> 6, c = idx & 63;
      ws[o][c] = Ww[(o0 + o)*256 + ch*64 + c];
    }
    __syncthreads();
    for (int c = 0; c < 64; ++c) {
      float wv[4], yv[4];
      #pragma unroll
      for (int i = 0; i < 4; ++i) wv[i] = ws[oq*4+i][c];
      #pragma unroll
      for (int j = 0; j < 4; ++j) yv[j] = ys[nq*4+j][c];
      #pragma unroll
      for (int i = 0; i < 4; ++i)
        #pragma unroll
        for (int j = 0; j < 4; ++j) acc[i][j] += wv[i]*yv[j];
    }
  }
  __syncthreads();
  #pragma unroll
  for (int i = 0; i < 4; ++i)
    #pragma unroll
    for (int j = 0; j < 4; ++j)
      ys[oq*4+i][nq*4+j] = acc[i][j]*ssc[oq*4+i] + ssh[oq*4+i];
  __syncthreads();
  const int nl = t & 63, og = t >> 6;
  for (int i = 0; i < 16; ++i) {
    int o = og*16 + i;
    long gidx = ((long)(b*Cn + o0 + o))*Nn + n0 + nl;
    out[gidx] = ys[o][nl] + x[gidx];
  }
}

extern "C" void kernel_launch(void* const* d_in, const int* in_sizes, int n_in,
                              void* d_out, int out_size, void* d_ws, size_t ws_size,
                              hipStream_t stream)
{
  const float* x       = (const float*)d_in[0];
  const float* g_w     = (const float*)d_in[1];
  const float* g_b     = (const float*)d_in[2];
  const float* theta_w = (const float*)d_in[3];
  const float* theta_b = (const float*)d_in[4];
  const float* phi_w   = (const float*)d_in[5];
  const float* phi_b   = (const float*)d_in[6];
  const float* W_w     = (const float*)d_in[7];
  const float* W_b     = (const float*)d_in[8];
  const float* bn_g    = (const float*)d_in[9];
  const float* bn_b    = (const float*)d_in[10];
  const float* bn_m    = (const float*)d_in[11];
  const float* bn_v    = (const float*)d_in[12];
  float* out = (float*)d_out;

  bf16* wsb = (bf16*)d_ws;
  bf16* Q = wsb;                 // B*N*64  = 2,097,152
  bf16* K = wsb + 2097152;       // B*M*64  =   524,288
  bf16* V = wsb + 2621440;       // B*M*256 = 2,097,152
  bf16* Y = wsb + 4718592;       // B*N*256 = 8,388,608  (total 26.2 MB)

  theta_kernel<<<dim3(32, Bn), 256, 0, stream>>>(x, theta_w, theta_b, Q);
  phi_kernel  <<<dim3(32, Bn), 256, 0, stream>>>(x, phi_w, phi_b, K);
  g_kernel    <<<dim3(32, 4, Bn), 256, 0, stream>>>(x, g_w, g_b, V);
  attn_kernel <<<dim3(128, Bn), 256, 0, stream>>>(Q, K, V, Y);
  wconv_kernel<<<dim3(64, 4, Bn), 256, 0, stream>>>(Y, W_w, W_b, bn_g, bn_b, bn_m, bn_v, x, out);
}

// Round 3
// 411.741 us; speedup vs baseline: 2.0528x; 2.0528x over previous
//
#include <hip/hip_runtime.h>
#include <hip/hip_bf16.h>

typedef __hip_bfloat16 bf16;
typedef unsigned short ushort;
typedef unsigned int uint;
typedef __attribute__((ext_vector_type(8))) short short8;
typedef __attribute__((ext_vector_type(4))) float f32x4;

#define Bn 8
#define Cn 256
#define Nn 4096          // H*W
#define Mn 1024          // pooled
#define EPSf 1e-5f

__device__ __forceinline__ float b2f(const bf16 v){ return __bfloat162float(v); }
__device__ __forceinline__ ushort f2bu(float f){
  uint u = __float_as_uint(f);
  return (ushort)((u + 0x7FFFu + ((u >> 16) & 1u)) >> 16);
}

// ---------------- theta: Q[b][n][64] = theta_w(64x64) @ x[b][0:64][n] + theta_b
__global__ __launch_bounds__(256) void theta_kernel(
    const float* __restrict__ x, const float* __restrict__ tw, const float* __restrict__ tb,
    bf16* __restrict__ Q)
{
  __shared__ float xs[64][130];
  __shared__ float ws[64][65];
  const int t = threadIdx.x;
  const int hr = blockIdx.x, b = blockIdx.y;
  const long xbase = ((long)b*Cn)*Nn + hr*128;
  for (int i = 0; i < 32; ++i) {
    int idx = t + i*256; int c = idx >> 7, p = idx & 127;
    xs[c][p] = x[xbase + (long)c*Nn + p];
  }
  for (int i = 0; i < 16; ++i) {
    int idx = t + i*256; int o = idx >> 6, c = idx & 63;
    ws[o][c] = tw[o*64 + c];
  }
  __syncthreads();
  const int oq = t >> 4, pq = t & 15;
  int pp[8];
  #pragma unroll
  for (int j = 0; j < 8; ++j) pp[j] = pq*8 + ((j + pq + (pq>>2)) & 7);
  float acc[4][8];
  #pragma unroll
  for (int i = 0; i < 4; ++i)
    #pragma unroll
    for (int j = 0; j < 8; ++j) acc[i][j] = 0.f;
  for (int c = 0; c < 64; ++c) {
    float wv[4], xv[8];
    #pragma unroll
    for (int i = 0; i < 4; ++i) wv[i] = ws[oq*4+i][c];
    #pragma unroll
    for (int j = 0; j < 8; ++j) xv[j] = xs[c][pp[j]];
    #pragma unroll
    for (int i = 0; i < 4; ++i)
      #pragma unroll
      for (int j = 0; j < 8; ++j) acc[i][j] += wv[i]*xv[j];
  }
  __syncthreads();
  #pragma unroll
  for (int i = 0; i < 4; ++i) {
    float bias = tb[oq*4+i];
    #pragma unroll
    for (int j = 0; j < 8; ++j) xs[oq*4+i][pp[j]] = acc[i][j] + bias;
  }
  __syncthreads();
  const int o = t & 63, g = t >> 6;
  const long qbase = ((long)b*Nn + hr*128)*64;
  for (int i = 0; i < 32; ++i) {
    int p = g*32 + i;
    Q[qbase + (long)p*64 + o] = __float2bfloat16(xs[o][p]);
  }
}

// ---------------- phi: K[b][m][64] = maxpool2(phi_w(64x192) @ x[b][64:256] + phi_b)
__global__ __launch_bounds__(256) void phi_kernel(
    const float* __restrict__ x, const float* __restrict__ pw, const float* __restrict__ pb,
    bf16* __restrict__ K)
{
  __shared__ float xs[64][130];
  __shared__ float ws[64][65];
  const int t = threadIdx.x;
  const int hp = blockIdx.x, b = blockIdx.y;
  const int oq = t >> 4, pq = t & 15;
  int pp[8];
  #pragma unroll
  for (int j = 0; j < 8; ++j) pp[j] = pq*8 + ((j + pq + (pq>>2)) & 7);
  float acc[4][8];
  #pragma unroll
  for (int i = 0; i < 4; ++i)
    #pragma unroll
    for (int j = 0; j < 8; ++j) acc[i][j] = 0.f;
  for (int ch = 0; ch < 3; ++ch) {
    __syncthreads();
    const long xbase = ((long)b*Cn + 64 + ch*64)*Nn + hp*128;
    for (int i = 0; i < 32; ++i) {
      int idx = t + i*256; int c = idx >> 7, p = idx & 127;
      xs[c][p] = x[xbase + (long)c*Nn + p];
    }
    for (int i = 0; i < 16; ++i) {
      int idx = t + i*256; int o = idx >> 6, c = idx & 63;
      ws[o][c] = pw[o*192 + ch*64 + c];
    }
    __syncthreads();
    for (int c = 0; c < 64; ++c) {
      float wv[4], xv[8];
      #pragma unroll
      for (int i = 0; i < 4; ++i) wv[i] = ws[oq*4+i][c];
      #pragma unroll
      for (int j = 0; j < 8; ++j) xv[j] = xs[c][pp[j]];
      #pragma unroll
      for (int i = 0; i < 4; ++i)
        #pragma unroll
        for (int j = 0; j < 8; ++j) acc[i][j] += wv[i]*xv[j];
    }
  }
  __syncthreads();
  #pragma unroll
  for (int i = 0; i < 4; ++i) {
    float bias = pb[oq*4+i];
    #pragma unroll
    for (int j = 0; j < 8; ++j) xs[oq*4+i][pp[j]] = acc[i][j] + bias;
  }
  __syncthreads();
  const int o = t & 63, wq = t >> 6;
  for (int i = 0; i < 8; ++i) {
    int wp = wq*8 + i;
    float v = fmaxf(fmaxf(xs[o][2*wp], xs[o][2*wp+1]),
                    fmaxf(xs[o][64+2*wp], xs[o][64+2*wp+1]));
    K[((long)b*Mn + hp*32 + wp)*64 + o] = __float2bfloat16(v);
  }
}

// ---------------- g: Vt[b][c=256][m=1024] = transpose(maxpool2(g_w @ x + g_b))
// grid (32, 4, B): hp, o-chunk, b. block 256.
__global__ __launch_bounds__(256) void g_kernel(
    const float* __restrict__ x, const float* __restrict__ gw, const float* __restrict__ gb,
    bf16* __restrict__ Vt)
{
  __shared__ float xs[64][130];
  __shared__ float ws[64][65];
  const int t = threadIdx.x;
  const int hp = blockIdx.x, o0 = blockIdx.y*64, b = blockIdx.z;
  const int oq = t >> 4, pq = t & 15;
  int pp[8];
  #pragma unroll
  for (int j = 0; j < 8; ++j) pp[j] = pq*8 + ((j + pq + (pq>>2)) & 7);
  float acc[4][8];
  #pragma unroll
  for (int i = 0; i < 4; ++i)
    #pragma unroll
    for (int j = 0; j < 8; ++j) acc[i][j] = 0.f;
  for (int ch = 0; ch < 4; ++ch) {
    __syncthreads();
    const long xbase = ((long)b*Cn + ch*64)*Nn + hp*128;
    for (int i = 0; i < 32; ++i) {
      int idx = t + i*256; int c = idx >> 7, p = idx & 127;
      xs[c][p] = x[xbase + (long)c*Nn + p];
    }
    for (int i = 0; i < 16; ++i) {
      int idx = t + i*256; int o = idx >> 6, c = idx & 63;
      ws[o][c] = gw[(o0 + o)*256 + ch*64 + c];
    }
    __syncthreads();
    for (int c = 0; c < 64; ++c) {
      float wv[4], xv[8];
      #pragma unroll
      for (int i = 0; i < 4; ++i) wv[i] = ws[oq*4+i][c];
      #pragma unroll
      for (int j = 0; j < 8; ++j) xv[j] = xs[c][pp[j]];
      #pragma unroll
      for (int i = 0; i < 4; ++i)
        #pragma unroll
        for (int j = 0; j < 8; ++j) acc[i][j] += wv[i]*xv[j];
    }
  }
  __syncthreads();
  #pragma unroll
  for (int i = 0; i < 4; ++i) {
    float bias = gb[o0 + oq*4+i];
    #pragma unroll
    for (int j = 0; j < 8; ++j) xs[oq*4+i][pp[j]] = acc[i][j] + bias;
  }
  __syncthreads();
  // transposed write: channel-major Vt[b][c][m], coalesced along m
  const int wp = t & 31, og = t >> 5;
  for (int i = 0; i < 8; ++i) {
    int o = og*8 + i;
    float v = fmaxf(fmaxf(xs[o][2*wp], xs[o][2*wp+1]),
                    fmaxf(xs[o][64+2*wp], xs[o][64+2*wp+1]));
    Vt[((long)(b*256 + o0 + o))*1024 + hp*32 + wp] = __float2bfloat16(v);
  }
}

// ---------------- MFMA flash attention: Y[b][n][256]
// grid (128, B): 32-row Q tiles; 16 iterations of 64-key tiles.
__global__ __launch_bounds__(256) void attn_kernel(
    const bf16* __restrict__ Q, const bf16* __restrict__ K, const bf16* __restrict__ Vt,
    bf16* __restrict__ Y)
{
  __shared__ __align__(16) ushort Qs[32*72];
  __shared__ __align__(16) ushort Ks[64*72];
  __shared__ __align__(16) ushort Vs[256*72];
  __shared__ __align__(16) float  Ss[32*68];
  __shared__ float m_sh[32], l_sh[32], a_sh[32];

  const int t = threadIdx.x;
  const int b = blockIdx.y, q0 = blockIdx.x*32;
  const int lane = t & 63, w = t >> 6;
  const int rt = w & 1;            // S/O row-tile (16 rows)
  const int cb = (w >> 1) * 128;   // O col base for PV
  const int ql = lane & 15, quad = lane >> 4;

  // stage Q (32 x 64)
  {
    int row = t >> 3, ch = t & 7;
    *(uint4*)(Qs + row*72 + ch*8) =
        *(const uint4*)(Q + ((long)(b*Nn) + q0 + row)*64 + ch*8);
  }
  if (t < 32) { m_sh[t] = -3e38f; l_sh[t] = 0.f; }
  __syncthreads();

  // preload Q A-frags: A[m=lane&15][k=quad*8+j], k-steps 0/1
  short8 aQ0 = *(const short8*)(Qs + (rt*16 + ql)*72 + quad*8);
  short8 aQ1 = *(const short8*)(Qs + (rt*16 + ql)*72 + 32 + quad*8);

  f32x4 acc[8];
  #pragma unroll
  for (int i = 0; i < 8; ++i) acc[i] = (f32x4){0.f, 0.f, 0.f, 0.f};

  for (int mt = 0; mt < 16; ++mt) {
    const int m0 = mt*64;
    __syncthreads();  // prev PV reads of Ss/Vs done
    {
      int ch = t & 7;
      #pragma unroll
      for (int i = 0; i < 2; ++i) {
        int row = (t>>3) + 32*i;
        *(uint4*)(Ks + row*72 + ch*8) =
            *(const uint4*)(K + ((long)b*Mn + m0 + row)*64 + ch*8);
      }
      #pragma unroll
      for (int p = 0; p < 8; ++p) {
        int n = (t>>3) + 32*p;
        *(uint4*)(Vs + n*72 + ch*8) =
            *(const uint4*)(Vt + ((long)(b*256 + n))*1024 + m0 + ch*8);
      }
    }
    __syncthreads();
    // QK^T: wave -> S rows rt*16..+15, cols (w>>1)*32..+31
    {
      int ct0 = (w >> 1)*2;
      #pragma unroll
      for (int ci = 0; ci < 2; ++ci) {
        int ct = ct0 + ci;
        f32x4 s = (f32x4){0.f, 0.f, 0.f, 0.f};
        short8 b0 = *(const short8*)(Ks + (ct*16 + ql)*72 + quad*8);
        short8 b1 = *(const short8*)(Ks + (ct*16 + ql)*72 + 32 + quad*8);
        s = __builtin_amdgcn_mfma_f32_16x16x32_bf16(aQ0, b0, s, 0, 0, 0);
        s = __builtin_amdgcn_mfma_f32_16x16x32_bf16(aQ1, b1, s, 0, 0, 0);
        #pragma unroll
        for (int r = 0; r < 4; ++r)    // C: col=lane&15, row=quad*4+r
          Ss[(rt*16 + quad*4 + r)*68 + ct*16 + ql] = s[r];
      }
    }
    __syncthreads();
    // online softmax: 8 threads per row, 8 cols each
    {
      int row = t >> 3, c0 = (t & 7)*8;
      float v[8];
      #pragma unroll
      for (int i = 0; i < 8; ++i) v[i] = Ss[row*68 + c0 + i];
      float mx = v[0];
      #pragma unroll
      for (int i = 1; i < 8; ++i) mx = fmaxf(mx, v[i]);
      #pragma unroll
      for (int off = 1; off < 8; off <<= 1) mx = fmaxf(mx, __shfl_xor(mx, off, 64));
      float mo = m_sh[row];
      float mn = fmaxf(mo, mx);
      float alpha = __expf(mo - mn);
      float sum = 0.f;
      #pragma unroll
      for (int i = 0; i < 8; ++i) { v[i] = __expf(v[i] - mn); sum += v[i]; }
      #pragma unroll
      for (int i = 0; i < 8; ++i) Ss[row*68 + c0 + i] = v[i];
      #pragma unroll
      for (int off = 1; off < 8; off <<= 1) sum += __shfl_xor(sum, off, 64);
      if ((t & 7) == 0) {
        m_sh[row] = mn;
        l_sh[row] = l_sh[row]*alpha + sum;
        a_sh[row] = alpha;
      }
    }
    __syncthreads();
    // rescale accumulators, then P·V
    {
      float al[4];
      #pragma unroll
      for (int r = 0; r < 4; ++r) al[r] = a_sh[rt*16 + quad*4 + r];
      #pragma unroll
      for (int i = 0; i < 8; ++i)
        #pragma unroll
        for (int r = 0; r < 4; ++r) acc[i][r] *= al[r];
      short8 aP0, aP1;
      {
        const float* ps = Ss + (rt*16 + ql)*68 + quad*8;
        #pragma unroll
        for (int j = 0; j < 8; ++j) aP0[j] = (short)f2bu(ps[j]);
        #pragma unroll
        for (int j = 0; j < 8; ++j) aP1[j] = (short)f2bu(ps[32 + j]);
      }
      #pragma unroll
      for (int ci = 0; ci < 8; ++ci) {
        short8 b0 = *(const short8*)(Vs + (cb + ci*16 + ql)*72 + quad*8);
        short8 b1 = *(const short8*)(Vs + (cb + ci*16 + ql)*72 + 32 + quad*8);
        acc[ci] = __builtin_amdgcn_mfma_f32_16x16x32_bf16(aP0, b0, acc[ci], 0, 0, 0);
        acc[ci] = __builtin_amdgcn_mfma_f32_16x16x32_bf16(aP1, b1, acc[ci], 0, 0, 0);
      }
    }
  }
  // epilogue: divide by l, store Y bf16 [n][256]
  float inv[4];
  #pragma unroll
  for (int r = 0; r < 4; ++r) inv[r] = 1.f / l_sh[rt*16 + quad*4 + r];
  #pragma unroll
  for (int ci = 0; ci < 8; ++ci)
    #pragma unroll
    for (int r = 0; r < 4; ++r) {
      int row = rt*16 + quad*4 + r, col = cb + ci*16 + ql;
      Y[((long)(b*Nn) + q0 + row)*256 + col] = __float2bfloat16(acc[ci][r]*inv[r]);
    }
}

// ---------------- W conv + BN + residual
__global__ __launch_bounds__(256) void wconv_kernel(
    const bf16* __restrict__ Y, const float* __restrict__ Ww, const float* __restrict__ Wb,
    const float* __restrict__ gamma, const float* __restrict__ beta,
    const float* __restrict__ mean, const float* __restrict__ var,
    const float* __restrict__ x, float* __restrict__ out)
{
  __shared__ float ys[64][65];
  __shared__ float ws[64][65];
  __shared__ float ssc[64], ssh[64];
  const int t = threadIdx.x;
  const int n0 = blockIdx.x*64, o0 = blockIdx.y*64, b = blockIdx.z;
  if (t < 64) {
    int o = o0 + t;
    float sc = gamma[o] * rsqrtf(var[o] + EPSf);
    ssc[t] = sc;
    ssh[t] = (Wb[o] - mean[o])*sc + beta[o];
  }
  const int oq = t >> 4, nq = t & 15;
  float acc[4][4];
  #pragma unroll
  for (int i = 0; i < 4; ++i)
    #pragma unroll
    for (int j = 0; j < 4; ++j) acc[i][j] = 0.f;
  for (int ch = 0; ch < 4; ++ch) {
    __syncthreads();
    for (int i = 0; i < 16; ++i) {
      int idx = t + i*256; int n = idx >> 6, c = idx & 63;
      ys[n][c] = b2f(Y[((long)b*Nn + n0 + n)*256 + ch*64 + c]);
    }
    for (int i = 0; i < 16; ++i) {
      int idx = t + i*256; int o = idx >> 6, c = idx & 63;
      ws[o][c] = Ww[(o0 + o)*256 + ch*64 + c];
    }
    __syncthreads();
    for (int c = 0; c < 64; ++c) {
      float wv[4], yv[4];
      #pragma unroll
      for (int i = 0; i < 4; ++i) wv[i] = ws[oq*4+i][c];
      #pragma unroll
      for (int j = 0; j < 4; ++j) yv[j] = ys[nq*4+j][c];
      #pragma unroll
      for (int i = 0; i < 4; ++i)
        #pragma unroll
        for (int j = 0; j < 4; ++j) acc[i][j] += wv[i]*yv[j];
    }
  }
  __syncthreads();
  #pragma unroll
  for (int i = 0; i < 4; ++i)
    #pragma unroll
    for (int j = 0; j < 4; ++j)
      ys[oq*4+i][nq*4+j] = acc[i][j]*ssc[oq*4+i] + ssh[oq*4+i];
  __syncthreads();
  const int nl = t & 63, og = t >> 6;
  for (int i = 0; i < 16; ++i) {
    int o = og*16 + i;
    long gidx = ((long)(b*Cn + o0 + o))*Nn + n0 + nl;
    out[gidx] = ys[o][nl] + x[gidx];
  }
}

extern "C" void kernel_launch(void* const* d_in, const int* in_sizes, int n_in,
                              void* d_out, int out_size, void* d_ws, size_t ws_size,
                              hipStream_t stream)
{
  const float* x       = (const float*)d_in[0];
  const float* g_w     = (const float*)d_in[1];
  const float* g_b     = (const float*)d_in[2];
  const float* theta_w = (const float*)d_in[3];
  const float* theta_b = (const float*)d_in[4];
  const float* phi_w   = (const float*)d_in[5];
  const float* phi_b   = (const float*)d_in[6];
  const float* W_w     = (const float*)d_in[7];
  const float* W_b     = (const float*)d_in[8];
  const float* bn_g    = (const float*)d_in[9];
  const float* bn_b    = (const float*)d_in[10];
  const float* bn_m    = (const float*)d_in[11];
  const float* bn_v    = (const float*)d_in[12];
  float* out = (float*)d_out;

  bf16* wsb = (bf16*)d_ws;
  bf16* Q  = wsb;                 // B*N*64    = 2,097,152
  bf16* K  = wsb + 2097152;       // B*M*64    =   524,288
  bf16* Vt = wsb + 2621440;       // B*256*M   = 2,097,152 (channel-major)
  bf16* Y  = wsb + 4718592;       // B*N*256   = 8,388,608

  theta_kernel<<<dim3(32, Bn), 256, 0, stream>>>(x, theta_w, theta_b, Q);
  phi_kernel  <<<dim3(32, Bn), 256, 0, stream>>>(x, phi_w, phi_b, K);
  g_kernel    <<<dim3(32, 4, Bn), 256, 0, stream>>>(x, g_w, g_b, Vt);
  attn_kernel <<<dim3(128, Bn), 256, 0, stream>>>(Q, K, Vt, Y);
  wconv_kernel<<<dim3(64, 4, Bn), 256, 0, stream>>>(Y, W_w, W_b, bn_g, bn_b, bn_m, bn_v, x, out);
}

// Round 4
// 220.749 us; speedup vs baseline: 3.8289x; 1.8652x over previous
//
#include <hip/hip_runtime.h>
#include <hip/hip_bf16.h>

typedef __hip_bfloat16 bf16;
typedef unsigned short ushort;
typedef unsigned int uint;
typedef __attribute__((ext_vector_type(8))) short short8;
typedef __attribute__((ext_vector_type(4))) float f32x4;

#define Bn 8
#define Cn 256
#define Nn 4096          // H*W
#define Mn 1024          // pooled
#define EPSf 1e-5f

__device__ __forceinline__ float b2f(const bf16 v){ return __bfloat162float(v); }
__device__ __forceinline__ ushort f2bu(float f){
  uint u = __float_as_uint(f);
  return (ushort)((u + 0x7FFFu + ((u >> 16) & 1u)) >> 16);
}
__device__ __forceinline__ float bu2f(ushort u){
  uint x = ((uint)u) << 16;
  return __uint_as_float(x);
}

// ---------------- transpose: x[b][c][p] fp32 -> xT[b][p][c] bf16
// grid (64 p-tiles, 4 c-tiles, 8 b), block 256
__global__ __launch_bounds__(256) void transpose_kernel(
    const float* __restrict__ x, bf16* __restrict__ xT)
{
  __shared__ float xs[64][65];
  const int t = threadIdx.x;
  const int p0 = blockIdx.x*64, c0 = blockIdx.y*64, b = blockIdx.z;
  #pragma unroll
  for (int i = 0; i < 16; ++i) {
    int idx = t + i*256; int cl = idx >> 6, pl = idx & 63;
    xs[cl][pl] = x[((long)(b*Cn) + c0 + cl)*Nn + p0 + pl];
  }
  __syncthreads();
  ushort* xTu = (ushort*)xT;
  #pragma unroll
  for (int i = 0; i < 8; ++i) {
    int idx = t + i*256; int pl = idx >> 5, cp = idx & 31;
    uint u = (uint)f2bu(xs[cp*2][pl]) | ((uint)f2bu(xs[cp*2+1][pl]) << 16);
    *(uint*)(xTu + ((long)(b*Nn) + p0 + pl)*Cn + c0 + cp*2) = u;
  }
}

// ---------------- build combined weights Wcomb[384][256] bf16 + bcomb[384] fp32
__global__ __launch_bounds__(256) void wcomb_kernel(
    const float* __restrict__ tw, const float* __restrict__ tb,
    const float* __restrict__ pw, const float* __restrict__ pb,
    const float* __restrict__ gw, const float* __restrict__ gb,
    bf16* __restrict__ Wcomb, float* __restrict__ bcomb)
{
  const int r = blockIdx.x, c = threadIdx.x;
  float v;
  if (r < 64)        v = (c < 64)  ? tw[r*64 + c]            : 0.f;
  else if (r < 128)  v = (c >= 64) ? pw[(r-64)*192 + (c-64)] : 0.f;
  else               v = gw[(r-128)*256 + c];
  Wcomb[r*256 + c] = __float2bfloat16(v);
  if (c == 0)
    bcomb[r] = (r < 64) ? tb[r] : (r < 128) ? pb[r-64] : gb[r-128];
}

// ---------------- fused front GEMM: pre[b][p][384] = xT[p][c] @ Wcomb^T + bcomb
// grid (32 p-tiles, 3 o-tiles, 8 b), block 256 (4 waves, 2x2 of 64x64)
__global__ __launch_bounds__(256) void gemm384_kernel(
    const bf16* __restrict__ xT, const bf16* __restrict__ Wcomb,
    const float* __restrict__ bcomb, bf16* __restrict__ pre)
{
  __shared__ __align__(16) ushort As[128*40];
  __shared__ __align__(16) ushort Bs[128*40];
  const int t = threadIdx.x;
  const int p0 = blockIdx.x*128, o0 = blockIdx.y*128, b = blockIdx.z;
  const int lane = t & 63, w = t >> 6;
  const int ql = lane & 15, quad = lane >> 4;
  const int wm = (w & 1)*64, wn = (w >> 1)*64;
  const ushort* xTu = (const ushort*)xT;
  const ushort* Wu  = (const ushort*)Wcomb;

  f32x4 acc[4][4];
  #pragma unroll
  for (int i = 0; i < 4; ++i)
    #pragma unroll
    for (int j = 0; j < 4; ++j) acc[i][j] = (f32x4){0.f,0.f,0.f,0.f};

  for (int kc = 0; kc < 8; ++kc) {
    __syncthreads();
    #pragma unroll
    for (int i = 0; i < 2; ++i) {
      int idx = t + i*256; int r = idx >> 2, cq = idx & 3;
      *(uint4*)(As + r*40 + cq*8) =
          *(const uint4*)(xTu + ((long)(b*Nn) + p0 + r)*Cn + kc*32 + cq*8);
      *(uint4*)(Bs + r*40 + cq*8) =
          *(const uint4*)(Wu + (o0 + r)*Cn + kc*32 + cq*8);
    }
    __syncthreads();
    short8 aF[4], bF[4];
    #pragma unroll
    for (int mi = 0; mi < 4; ++mi)
      aF[mi] = *(const short8*)(As + (wm + mi*16 + ql)*40 + quad*8);
    #pragma unroll
    for (int ni = 0; ni < 4; ++ni)
      bF[ni] = *(const short8*)(Bs + (wn + ni*16 + ql)*40 + quad*8);
    #pragma unroll
    for (int mi = 0; mi < 4; ++mi)
      #pragma unroll
      for (int ni = 0; ni < 4; ++ni)
        acc[mi][ni] = __builtin_amdgcn_mfma_f32_16x16x32_bf16(aF[mi], bF[ni], acc[mi][ni], 0, 0, 0);
  }
  // epilogue: add bias, store bf16 (C: col=lane&15 -> o, row=quad*4+r -> p)
  float bias[4];
  #pragma unroll
  for (int ni = 0; ni < 4; ++ni) bias[ni] = bcomb[o0 + wn + ni*16 + ql];
  #pragma unroll
  for (int mi = 0; mi < 4; ++mi)
    #pragma unroll
    for (int ni = 0; ni < 4; ++ni)
      #pragma unroll
      for (int r = 0; r < 4; ++r) {
        int row = p0 + wm + mi*16 + quad*4 + r;
        int col = o0 + wn + ni*16 + ql;
        pre[((long)(b*Nn) + row)*384 + col] = __float2bfloat16(acc[mi][ni][r] + bias[ni]);
      }
}

// ---------------- poolK: K[b][m][64] = maxpool2 of pre slice o 64..128
// grid (32 hp, 8 b), block 256
__global__ __launch_bounds__(256) void poolK_kernel(
    const bf16* __restrict__ pre, bf16* __restrict__ K)
{
  const int t = threadIdx.x;
  const int hp = blockIdx.x, b = blockIdx.y;
  const ushort* pu = (const ushort*)pre;
  ushort* Ku = (ushort*)K;
  #pragma unroll
  for (int s = 0; s < 4; ++s) {
    int idx = t + s*256;
    int op = idx & 31, wp = idx >> 5;
    long p00 = (long)(b*Nn) + (2*hp)*64 + 2*wp;
    uint u0 = *(const uint*)(pu + (p00    )*384 + 64 + op*2);
    uint u1 = *(const uint*)(pu + (p00 + 1)*384 + 64 + op*2);
    uint u2 = *(const uint*)(pu + (p00 + 64)*384 + 64 + op*2);
    uint u3 = *(const uint*)(pu + (p00 + 65)*384 + 64 + op*2);
    float lo = fmaxf(fmaxf(bu2f((ushort)u0), bu2f((ushort)u1)),
                     fmaxf(bu2f((ushort)u2), bu2f((ushort)u3)));
    float hi = fmaxf(fmaxf(bu2f((ushort)(u0>>16)), bu2f((ushort)(u1>>16))),
                     fmaxf(bu2f((ushort)(u2>>16)), bu2f((ushort)(u3>>16))));
    uint r = (uint)f2bu(lo) | ((uint)f2bu(hi) << 16);
    *(uint*)(Ku + ((long)(b*Mn) + hp*32 + wp)*64 + op*2) = r;
  }
}

// ---------------- poolVt: Vt[b][c=256][m=1024] = transpose(maxpool2(pre slice o 128..384))
// grid (32 hp, 8 b), block 256
__global__ __launch_bounds__(256) void poolVt_kernel(
    const bf16* __restrict__ pre, bf16* __restrict__ Vt)
{
  __shared__ ushort Ps[256*36];
  const int t = threadIdx.x;
  const int hp = blockIdx.x, b = blockIdx.y;
  const ushort* pu = (const ushort*)pre;
  ushort* Vu = (ushort*)Vt;
  #pragma unroll
  for (int s = 0; s < 16; ++s) {
    int idx = t + s*256;
    int cp = idx & 127, wp = idx >> 7;
    long p00 = (long)(b*Nn) + (2*hp)*64 + 2*wp;
    uint u0 = *(const uint*)(pu + (p00    )*384 + 128 + cp*2);
    uint u1 = *(const uint*)(pu + (p00 + 1)*384 + 128 + cp*2);
    uint u2 = *(const uint*)(pu + (p00 + 64)*384 + 128 + cp*2);
    uint u3 = *(const uint*)(pu + (p00 + 65)*384 + 128 + cp*2);
    float lo = fmaxf(fmaxf(bu2f((ushort)u0), bu2f((ushort)u1)),
                     fmaxf(bu2f((ushort)u2), bu2f((ushort)u3)));
    float hi = fmaxf(fmaxf(bu2f((ushort)(u0>>16)), bu2f((ushort)(u1>>16))),
                     fmaxf(bu2f((ushort)(u2>>16)), bu2f((ushort)(u3>>16))));
    Ps[(cp*2  )*36 + wp] = f2bu(lo);
    Ps[(cp*2+1)*36 + wp] = f2bu(hi);
  }
  __syncthreads();
  #pragma unroll
  for (int s = 0; s < 8; ++s) {
    int idx = t + s*256;
    int c = idx >> 3, wq = idx & 7;
    *(uint2*)(Vu + ((long)(b*Cn) + c)*Mn + hp*32 + wq*4) =
        *(const uint2*)(Ps + c*36 + wq*4);
  }
}

// ---------------- MFMA flash attention: Y[b][n][256]; Q = pre[:, :, 0:64] (pitch 384)
// grid (128, B): 32-row Q tiles; 16 iterations of 64-key tiles.
__global__ __launch_bounds__(256) void attn_kernel(
    const bf16* __restrict__ pre, const bf16* __restrict__ K, const bf16* __restrict__ Vt,
    bf16* __restrict__ Y)
{
  __shared__ __align__(16) ushort Qs[32*72];
  __shared__ __align__(16) ushort Ks[64*72];
  __shared__ __align__(16) ushort Vs[256*72];
  __shared__ __align__(16) float  Ss[32*68];
  __shared__ float m_sh[32], l_sh[32], a_sh[32];

  const int t = threadIdx.x;
  const int b = blockIdx.y, q0 = blockIdx.x*32;
  const int lane = t & 63, w = t >> 6;
  const int rt = w & 1;            // S/O row-tile (16 rows)
  const int cb = (w >> 1) * 128;   // O col base for PV
  const int ql = lane & 15, quad = lane >> 4;

  // stage Q (32 x 64) from pre (pitch 384)
  {
    int row = t >> 3, ch = t & 7;
    *(uint4*)(Qs + row*72 + ch*8) =
        *(const uint4*)(pre + ((long)(b*Nn) + q0 + row)*384 + ch*8);
  }
  if (t < 32) { m_sh[t] = -3e38f; l_sh[t] = 0.f; }
  __syncthreads();

  short8 aQ0 = *(const short8*)(Qs + (rt*16 + ql)*72 + quad*8);
  short8 aQ1 = *(const short8*)(Qs + (rt*16 + ql)*72 + 32 + quad*8);

  f32x4 acc[8];
  #pragma unroll
  for (int i = 0; i < 8; ++i) acc[i] = (f32x4){0.f, 0.f, 0.f, 0.f};

  for (int mt = 0; mt < 16; ++mt) {
    const int m0 = mt*64;
    __syncthreads();
    {
      int ch = t & 7;
      #pragma unroll
      for (int i = 0; i < 2; ++i) {
        int row = (t>>3) + 32*i;
        *(uint4*)(Ks + row*72 + ch*8) =
            *(const uint4*)(K + ((long)b*Mn + m0 + row)*64 + ch*8);
      }
      #pragma unroll
      for (int p = 0; p < 8; ++p) {
        int n = (t>>3) + 32*p;
        *(uint4*)(Vs + n*72 + ch*8) =
            *(const uint4*)(Vt + ((long)(b*Cn + n))*Mn + m0 + ch*8);
      }
    }
    __syncthreads();
    {
      int ct0 = (w >> 1)*2;
      #pragma unroll
      for (int ci = 0; ci < 2; ++ci) {
        int ct = ct0 + ci;
        f32x4 s = (f32x4){0.f, 0.f, 0.f, 0.f};
        short8 b0 = *(const short8*)(Ks + (ct*16 + ql)*72 + quad*8);
        short8 b1 = *(const short8*)(Ks + (ct*16 + ql)*72 + 32 + quad*8);
        s = __builtin_amdgcn_mfma_f32_16x16x32_bf16(aQ0, b0, s, 0, 0, 0);
        s = __builtin_amdgcn_mfma_f32_16x16x32_bf16(aQ1, b1, s, 0, 0, 0);
        #pragma unroll
        for (int r = 0; r < 4; ++r)
          Ss[(rt*16 + quad*4 + r)*68 + ct*16 + ql] = s[r];
      }
    }
    __syncthreads();
    {
      int row = t >> 3, c0 = (t & 7)*8;
      float v[8];
      #pragma unroll
      for (int i = 0; i < 8; ++i) v[i] = Ss[row*68 + c0 + i];
      float mx = v[0];
      #pragma unroll
      for (int i = 1; i < 8; ++i) mx = fmaxf(mx, v[i]);
      #pragma unroll
      for (int off = 1; off < 8; off <<= 1) mx = fmaxf(mx, __shfl_xor(mx, off, 64));
      float mo = m_sh[row];
      float mn = fmaxf(mo, mx);
      float alpha = __expf(mo - mn);
      float sum = 0.f;
      #pragma unroll
      for (int i = 0; i < 8; ++i) { v[i] = __expf(v[i] - mn); sum += v[i]; }
      #pragma unroll
      for (int i = 0; i < 8; ++i) Ss[row*68 + c0 + i] = v[i];
      #pragma unroll
      for (int off = 1; off < 8; off <<= 1) sum += __shfl_xor(sum, off, 64);
      if ((t & 7) == 0) {
        m_sh[row] = mn;
        l_sh[row] = l_sh[row]*alpha + sum;
        a_sh[row] = alpha;
      }
    }
    __syncthreads();
    {
      float al[4];
      #pragma unroll
      for (int r = 0; r < 4; ++r) al[r] = a_sh[rt*16 + quad*4 + r];
      #pragma unroll
      for (int i = 0; i < 8; ++i)
        #pragma unroll
        for (int r = 0; r < 4; ++r) acc[i][r] *= al[r];
      short8 aP0, aP1;
      {
        const float* ps = Ss + (rt*16 + ql)*68 + quad*8;
        #pragma unroll
        for (int j = 0; j < 8; ++j) aP0[j] = (short)f2bu(ps[j]);
        #pragma unroll
        for (int j = 0; j < 8; ++j) aP1[j] = (short)f2bu(ps[32 + j]);
      }
      #pragma unroll
      for (int ci = 0; ci < 8; ++ci) {
        short8 b0 = *(const short8*)(Vs + (cb + ci*16 + ql)*72 + quad*8);
        short8 b1 = *(const short8*)(Vs + (cb + ci*16 + ql)*72 + 32 + quad*8);
        acc[ci] = __builtin_amdgcn_mfma_f32_16x16x32_bf16(aP0, b0, acc[ci], 0, 0, 0);
        acc[ci] = __builtin_amdgcn_mfma_f32_16x16x32_bf16(aP1, b1, acc[ci], 0, 0, 0);
      }
    }
  }
  float inv[4];
  #pragma unroll
  for (int r = 0; r < 4; ++r) inv[r] = 1.f / l_sh[rt*16 + quad*4 + r];
  #pragma unroll
  for (int ci = 0; ci < 8; ++ci)
    #pragma unroll
    for (int r = 0; r < 4; ++r) {
      int row = rt*16 + quad*4 + r, col = cb + ci*16 + ql;
      Y[((long)(b*Nn) + q0 + row)*256 + col] = __float2bfloat16(acc[ci][r]*inv[r]);
    }
}

// ---------------- wconv MFMA GEMM: out[b][o][n] = Ww @ Y^T, BN, +x
// grid (32 n-tiles, 2 o-tiles, 8 b), block 256 (4 waves, 2x2 of 64x64)
__global__ __launch_bounds__(256) void wconv_kernel(
    const bf16* __restrict__ Y, const float* __restrict__ Ww, const float* __restrict__ Wb,
    const float* __restrict__ gamma, const float* __restrict__ beta,
    const float* __restrict__ mean, const float* __restrict__ var,
    const float* __restrict__ x, float* __restrict__ out)
{
  __shared__ __align__(16) ushort As[128*40];
  __shared__ __align__(16) ushort Bs[128*40];
  __shared__ float ssc[128], ssh[128];
  const int t = threadIdx.x;
  const int n0 = blockIdx.x*128, o0 = blockIdx.y*128, b = blockIdx.z;
  const int lane = t & 63, w = t >> 6;
  const int ql = lane & 15, quad = lane >> 4;
  const int wm = (w & 1)*64, wn = (w >> 1)*64;
  const ushort* Yu = (const ushort*)Y;

  if (t < 128) {
    int o = o0 + t;
    float sc = gamma[o] * rsqrtf(var[o] + EPSf);
    ssc[t] = sc;
    ssh[t] = (Wb[o] - mean[o])*sc + beta[o];
  }

  f32x4 acc[4][4];
  #pragma unroll
  for (int i = 0; i < 4; ++i)
    #pragma unroll
    for (int j = 0; j < 4; ++j) acc[i][j] = (f32x4){0.f,0.f,0.f,0.f};

  for (int kc = 0; kc < 8; ++kc) {
    __syncthreads();
    // A: Ww rows (fp32 -> bf16)
    #pragma unroll
    for (int i = 0; i < 4; ++i) {
      int idx = t + i*256; int r = idx >> 3, cq = idx & 7;
      float4 v = *(const float4*)(Ww + (o0 + r)*Cn + kc*32 + cq*4);
      uint lo = (uint)f2bu(v.x) | ((uint)f2bu(v.y) << 16);
      uint hi = (uint)f2bu(v.z) | ((uint)f2bu(v.w) << 16);
      *(uint2*)(As + r*40 + cq*4) = make_uint2(lo, hi);
    }
    // B: Y rows
    #pragma unroll
    for (int i = 0; i < 2; ++i) {
      int idx = t + i*256; int r = idx >> 2, cq = idx & 3;
      *(uint4*)(Bs + r*40 + cq*8) =
          *(const uint4*)(Yu + ((long)(b*Nn) + n0 + r)*Cn + kc*32 + cq*8);
    }
    __syncthreads();
    short8 aF[4], bF[4];
    #pragma unroll
    for (int mi = 0; mi < 4; ++mi)
      aF[mi] = *(const short8*)(As + (wm + mi*16 + ql)*40 + quad*8);
    #pragma unroll
    for (int ni = 0; ni < 4; ++ni)
      bF[ni] = *(const short8*)(Bs + (wn + ni*16 + ql)*40 + quad*8);
    #pragma unroll
    for (int mi = 0; mi < 4; ++mi)
      #pragma unroll
      for (int ni = 0; ni < 4; ++ni)
        acc[mi][ni] = __builtin_amdgcn_mfma_f32_16x16x32_bf16(aF[mi], bF[ni], acc[mi][ni], 0, 0, 0);
  }
  // epilogue: BN + residual + fp32 store. C: col=lane&15 -> n, row=quad*4+r -> o
  #pragma unroll
  for (int mi = 0; mi < 4; ++mi)
    #pragma unroll
    for (int r = 0; r < 4; ++r) {
      int ol = wm + mi*16 + quad*4 + r;
      int o = o0 + ol;
      float sc = ssc[ol], sh = ssh[ol];
      #pragma unroll
      for (int ni = 0; ni < 4; ++ni) {
        int n = n0 + wn + ni*16 + ql;
        long gidx = ((long)(b*Cn + o))*Nn + n;
        out[gidx] = acc[mi][ni][r]*sc + sh + x[gidx];
      }
    }
}

extern "C" void kernel_launch(void* const* d_in, const int* in_sizes, int n_in,
                              void* d_out, int out_size, void* d_ws, size_t ws_size,
                              hipStream_t stream)
{
  const float* x       = (const float*)d_in[0];
  const float* g_w     = (const float*)d_in[1];
  const float* g_b     = (const float*)d_in[2];
  const float* theta_w = (const float*)d_in[3];
  const float* theta_b = (const float*)d_in[4];
  const float* phi_w   = (const float*)d_in[5];
  const float* phi_b   = (const float*)d_in[6];
  const float* W_w     = (const float*)d_in[7];
  const float* W_b     = (const float*)d_in[8];
  const float* bn_g    = (const float*)d_in[9];
  const float* bn_b    = (const float*)d_in[10];
  const float* bn_m    = (const float*)d_in[11];
  const float* bn_v    = (const float*)d_in[12];
  float* out = (float*)d_out;

  bf16* wsb = (bf16*)d_ws;
  bf16* xT    = wsb;                  // B*N*C   =  8,388,608  (aliased by Y later)
  bf16* Y     = wsb;                  // alias: xT dead after gemm384
  bf16* pre   = wsb + 8388608;        // B*N*384 = 12,582,912
  bf16* K     = wsb + 20971520;       // B*M*64  =    524,288
  bf16* Vt    = wsb + 21495808;       // B*C*M   =  2,097,152
  bf16* Wcomb = wsb + 23592960;       // 384*256 =     98,304
  float* bcomb = (float*)(wsb + 23691264);  // 384 fp32

  transpose_kernel<<<dim3(64, 4, Bn), 256, 0, stream>>>(x, xT);
  wcomb_kernel<<<dim3(384), 256, 0, stream>>>(theta_w, theta_b, phi_w, phi_b, g_w, g_b, Wcomb, bcomb);
  gemm384_kernel<<<dim3(32, 3, Bn), 256, 0, stream>>>(xT, Wcomb, bcomb, pre);
  poolK_kernel<<<dim3(32, Bn), 256, 0, stream>>>(pre, K);
  poolVt_kernel<<<dim3(32, Bn), 256, 0, stream>>>(pre, Vt);
  attn_kernel<<<dim3(128, Bn), 256, 0, stream>>>(pre, K, Vt, Y);
  wconv_kernel<<<dim3(32, 2, Bn), 256, 0, stream>>>(Y, W_w, W_b, bn_g, bn_b, bn_m, bn_v, x, out);
}

// Round 5
// 201.868 us; speedup vs baseline: 4.1870x; 1.0935x over previous
//
#include <hip/hip_runtime.h>
#include <hip/hip_bf16.h>

typedef __hip_bfloat16 bf16;
typedef unsigned short ushort;
typedef unsigned int uint;
typedef __attribute__((ext_vector_type(8))) short short8;
typedef __attribute__((ext_vector_type(4))) float f32x4;

#define Bn 8
#define Cn 256
#define Nn 4096          // H*W
#define Mn 1024          // pooled
#define EPSf 1e-5f

__device__ __forceinline__ float b2f(const bf16 v){ return __bfloat162float(v); }
__device__ __forceinline__ ushort f2bu(float f){
  uint u = __float_as_uint(f);
  return (ushort)((u + 0x7FFFu + ((u >> 16) & 1u)) >> 16);
}

// ---------------- transpose: x[b][c][p] fp32 -> xT[b][p][c] bf16
__global__ __launch_bounds__(256) void transpose_kernel(
    const float* __restrict__ x, bf16* __restrict__ xT)
{
  __shared__ float xs[64][65];
  const int t = threadIdx.x;
  const int p0 = blockIdx.x*64, c0 = blockIdx.y*64, b = blockIdx.z;
  #pragma unroll
  for (int i = 0; i < 16; ++i) {
    int idx = t + i*256; int cl = idx >> 6, pl = idx & 63;
    xs[cl][pl] = x[((long)(b*Cn) + c0 + cl)*Nn + p0 + pl];
  }
  __syncthreads();
  ushort* xTu = (ushort*)xT;
  #pragma unroll
  for (int i = 0; i < 8; ++i) {
    int idx = t + i*256; int pl = idx >> 5, cp = idx & 31;
    uint u = (uint)f2bu(xs[cp*2][pl]) | ((uint)f2bu(xs[cp*2+1][pl]) << 16);
    *(uint*)(xTu + ((long)(b*Nn) + p0 + pl)*Cn + c0 + cp*2) = u;
  }
}

// ---------------- build combined weights Wcomb[384][256] bf16 + bcomb[384] fp32
__global__ __launch_bounds__(256) void wcomb_kernel(
    const float* __restrict__ tw, const float* __restrict__ tb,
    const float* __restrict__ pw, const float* __restrict__ pb,
    const float* __restrict__ gw, const float* __restrict__ gb,
    bf16* __restrict__ Wcomb, float* __restrict__ bcomb)
{
  const int r = blockIdx.x, c = threadIdx.x;
  float v;
  if (r < 64)        v = (c < 64)  ? tw[r*64 + c]            : 0.f;
  else if (r < 128)  v = (c >= 64) ? pw[(r-64)*192 + (c-64)] : 0.f;
  else               v = gw[(r-128)*256 + c];
  Wcomb[r*256 + c] = __float2bfloat16(v);
  if (c == 0)
    bcomb[r] = (r < 64) ? tb[r] : (r < 128) ? pb[r-64] : gb[r-128];
}

// ---------------- fused front GEMM + pooling: emits Q, K, Vt directly
// grid (32 px (h-pairs), 3 o-tiles, 8 b), block 256 (4 waves, 2x2 of 64x64)
// p0 = px*128 covers h rows {2px, 2px+1} over full width 64.
__global__ __launch_bounds__(256) void gemm384_kernel(
    const bf16* __restrict__ xT, const bf16* __restrict__ Wcomb,
    const float* __restrict__ bcomb, bf16* __restrict__ Q,
    bf16* __restrict__ K, bf16* __restrict__ Vt)
{
  __shared__ union {
    struct { ushort As[128*40]; ushort Bs[128*40]; } g;
    float Pb[2][128][33];
  } sm;
  const int t = threadIdx.x;
  const int px = blockIdx.x, o0 = blockIdx.y*128, b = blockIdx.z;
  const int p0 = px*128;
  const int lane = t & 63, w = t >> 6;
  const int ql = lane & 15, quad = lane >> 4;
  const int wm = (w & 1)*64, wn = (w >> 1)*64;
  const ushort* xTu = (const ushort*)xT;
  const ushort* Wu  = (const ushort*)Wcomb;

  f32x4 acc[4][4];
  #pragma unroll
  for (int i = 0; i < 4; ++i)
    #pragma unroll
    for (int j = 0; j < 4; ++j) acc[i][j] = (f32x4){0.f,0.f,0.f,0.f};

  for (int kc = 0; kc < 8; ++kc) {
    __syncthreads();
    #pragma unroll
    for (int i = 0; i < 2; ++i) {
      int idx = t + i*256; int r = idx >> 2, cq = idx & 3;
      *(uint4*)(sm.g.As + r*40 + cq*8) =
          *(const uint4*)(xTu + ((long)(b*Nn) + p0 + r)*Cn + kc*32 + cq*8);
      *(uint4*)(sm.g.Bs + r*40 + cq*8) =
          *(const uint4*)(Wu + (o0 + r)*Cn + kc*32 + cq*8);
    }
    __syncthreads();
    short8 aF[4], bF[4];
    #pragma unroll
    for (int mi = 0; mi < 4; ++mi)
      aF[mi] = *(const short8*)(sm.g.As + (wm + mi*16 + ql)*40 + quad*8);
    #pragma unroll
    for (int ni = 0; ni < 4; ++ni)
      bF[ni] = *(const short8*)(sm.g.Bs + (wn + ni*16 + ql)*40 + quad*8);
    #pragma unroll
    for (int mi = 0; mi < 4; ++mi)
      #pragma unroll
      for (int ni = 0; ni < 4; ++ni)
        acc[mi][ni] = __builtin_amdgcn_mfma_f32_16x16x32_bf16(aF[mi], bF[ni], acc[mi][ni], 0, 0, 0);
  }
  float bias[4];
  #pragma unroll
  for (int ni = 0; ni < 4; ++ni) bias[ni] = bcomb[o0 + wn + ni*16 + ql];

  // Q: theta slice (o 0..63), no pooling. C: col=ql->o, row=quad*4+r->p
  if (o0 == 0 && wn == 0) {
    #pragma unroll
    for (int mi = 0; mi < 4; ++mi)
      #pragma unroll
      for (int ni = 0; ni < 4; ++ni)
        #pragma unroll
        for (int r = 0; r < 4; ++r) {
          int p = p0 + wm + mi*16 + quad*4 + r;
          Q[((long)(b*Nn) + p)*64 + ni*16 + ql] = __float2bfloat16(acc[mi][ni][r] + bias[ni]);
        }
  }
  __syncthreads();   // As/Bs dead; Pb reuses the LDS
  // pool: r-pairs in-lane (w-direction), h-parity via Pb
  if (o0 != 0 || wn == 64) {
    int g = w & 1;   // h parity (wm=64 -> h odd)
    #pragma unroll
    for (int mi = 0; mi < 4; ++mi)
      #pragma unroll
      for (int ni = 0; ni < 4; ++ni) {
        float a0 = acc[mi][ni][0] + bias[ni], a1 = acc[mi][ni][1] + bias[ni];
        float a2 = acc[mi][ni][2] + bias[ni], a3 = acc[mi][ni][3] + bias[ni];
        int o = wn + ni*16 + ql;
        int wp = mi*8 + quad*2;
        sm.Pb[g][o][wp]     = fmaxf(a0, a1);
        sm.Pb[g][o][wp + 1] = fmaxf(a2, a3);
      }
  }
  __syncthreads();
  if (o0 == 0) {
    // K[b][m][64] from o-local 64..127
    int wp = t & 31, og = t >> 5;
    ushort kv[8];
    #pragma unroll
    for (int j = 0; j < 8; ++j) {
      int o = 64 + og*8 + j;
      kv[j] = f2bu(fmaxf(sm.Pb[0][o][wp], sm.Pb[1][o][wp]));
    }
    *(uint4*)((ushort*)K + ((long)(b*Mn) + px*32 + wp)*64 + og*8) = *(uint4*)kv;
  } else {
    // Vt[b][c][m] from all 128 o-locals
    int ol = t >> 1, wp0 = (t & 1)*16;
    ushort vv[16];
    #pragma unroll
    for (int j = 0; j < 16; ++j)
      vv[j] = f2bu(fmaxf(sm.Pb[0][ol][wp0 + j], sm.Pb[1][ol][wp0 + j]));
    ushort* dst = (ushort*)Vt + ((long)(b*Cn) + (o0 - 128) + ol)*Mn + px*32 + wp0;
    *(uint4*)dst       = *(uint4*)(vv);
    *(uint4*)(dst + 8) = *(uint4*)(vv + 8);
  }
}

// ---------------- MFMA flash attention v2: Y[b][n][256]
// grid (64, B): 64-row Q blocks, 16 iterations of 64-key tiles.
// QK: wave w owns rows w*16..+15 x all 64 keys -> in-register softmax.
// PV: wave w owns rows (w&1)*32..+31 x cols (w>>1)*128..+127 (V-frag reuse x2).
__global__ __launch_bounds__(256) void attn_kernel(
    const bf16* __restrict__ Q, const bf16* __restrict__ K, const bf16* __restrict__ Vt,
    bf16* __restrict__ Y)
{
  __shared__ __align__(16) ushort Ks[64*72];
  __shared__ __align__(16) ushort Vs[256*72];
  __shared__ __align__(16) ushort Ps[64*72];
  __shared__ float a_sh[64];
  __shared__ float l_sh[64];

  const int t = threadIdx.x;
  const int b = blockIdx.y, q0 = blockIdx.x*64;
  const int lane = t & 63, w = t >> 6;
  const int ql = lane & 15, quad = lane >> 4;
  const int rql = w*16;                 // QK local row base
  const int pvr = (w & 1)*32;           // PV local row base
  const int pvc = (w >> 1)*128;         // PV col base
  const ushort* Qu = (const ushort*)Q;
  const ushort* Ku = (const ushort*)K;
  const ushort* Vu = (const ushort*)Vt;

  // Q A-frags direct from global: A[m=ql][k=quad*8+j]
  short8 aQ0 = *(const short8*)(Qu + ((long)(b*Nn) + q0 + rql + ql)*64 + quad*8);
  short8 aQ1 = *(const short8*)(Qu + ((long)(b*Nn) + q0 + rql + ql)*64 + 32 + quad*8);

  float mrow[4], lrow[4];
  #pragma unroll
  for (int r = 0; r < 4; ++r) { mrow[r] = -3e38f; lrow[r] = 0.f; }

  f32x4 acc[2][8];
  #pragma unroll
  for (int mi = 0; mi < 2; ++mi)
    #pragma unroll
    for (int ci = 0; ci < 8; ++ci) acc[mi][ci] = (f32x4){0.f,0.f,0.f,0.f};

  for (int mt = 0; mt < 16; ++mt) {
    const int m0 = mt*64;
    __syncthreads();
    {
      int ch = t & 7, rr = t >> 3;
      #pragma unroll
      for (int i = 0; i < 2; ++i) {
        int row = rr + 32*i;
        *(uint4*)(Ks + row*72 + ch*8) =
            *(const uint4*)(Ku + ((long)(b*Mn) + m0 + row)*64 + ch*8);
      }
      #pragma unroll
      for (int p = 0; p < 8; ++p) {
        int n = rr + 32*p;
        *(uint4*)(Vs + n*72 + ch*8) =
            *(const uint4*)(Vu + ((long)(b*Cn) + n)*Mn + m0 + ch*8);
      }
    }
    __syncthreads();
    // QK^T: rows rql+quad*4+r, all 64 keys in 4 col-tiles
    f32x4 s[4];
    #pragma unroll
    for (int ct = 0; ct < 4; ++ct) {
      short8 b0 = *(const short8*)(Ks + (ct*16 + ql)*72 + quad*8);
      short8 b1 = *(const short8*)(Ks + (ct*16 + ql)*72 + 32 + quad*8);
      s[ct] = (f32x4){0.f,0.f,0.f,0.f};
      s[ct] = __builtin_amdgcn_mfma_f32_16x16x32_bf16(aQ0, b0, s[ct], 0, 0, 0);
      s[ct] = __builtin_amdgcn_mfma_f32_16x16x32_bf16(aQ1, b1, s[ct], 0, 0, 0);
    }
    // in-register online softmax (reduce across 16 ql-lanes per quad)
    float alpha[4];
    #pragma unroll
    for (int r = 0; r < 4; ++r) {
      float mx = fmaxf(fmaxf(s[0][r], s[1][r]), fmaxf(s[2][r], s[3][r]));
      #pragma unroll
      for (int off = 1; off < 16; off <<= 1) mx = fmaxf(mx, __shfl_xor(mx, off, 64));
      float mn = fmaxf(mrow[r], mx);
      alpha[r] = __expf(mrow[r] - mn);
      mrow[r] = mn;
      float sum = 0.f;
      #pragma unroll
      for (int ct = 0; ct < 4; ++ct) { s[ct][r] = __expf(s[ct][r] - mn); sum += s[ct][r]; }
      #pragma unroll
      for (int off = 1; off < 16; off <<= 1) sum += __shfl_xor(sum, off, 64);
      lrow[r] = lrow[r]*alpha[r] + sum;
    }
    // write P (bf16) + alpha
    #pragma unroll
    for (int ct = 0; ct < 4; ++ct)
      #pragma unroll
      for (int r = 0; r < 4; ++r)
        Ps[(rql + quad*4 + r)*72 + ct*16 + ql] = f2bu(s[ct][r]);
    if (ql == 0) {
      #pragma unroll
      for (int r = 0; r < 4; ++r) a_sh[rql + quad*4 + r] = alpha[r];
    }
    __syncthreads();
    // PV: rescale acc, then P(32 rows) x V(64 keys x 128 cols)
    #pragma unroll
    for (int mi = 0; mi < 2; ++mi) {
      #pragma unroll
      for (int r = 0; r < 4; ++r) {
        float alv = a_sh[pvr + mi*16 + quad*4 + r];
        #pragma unroll
        for (int ci = 0; ci < 8; ++ci) acc[mi][ci][r] *= alv;
      }
    }
    short8 aP0[2], aP1[2];
    #pragma unroll
    for (int mi = 0; mi < 2; ++mi) {
      aP0[mi] = *(const short8*)(Ps + (pvr + mi*16 + ql)*72 + quad*8);
      aP1[mi] = *(const short8*)(Ps + (pvr + mi*16 + ql)*72 + 32 + quad*8);
    }
    #pragma unroll
    for (int ci = 0; ci < 8; ++ci) {
      short8 b0 = *(const short8*)(Vs + (pvc + ci*16 + ql)*72 + quad*8);
      short8 b1 = *(const short8*)(Vs + (pvc + ci*16 + ql)*72 + 32 + quad*8);
      #pragma unroll
      for (int mi = 0; mi < 2; ++mi) {
        acc[mi][ci] = __builtin_amdgcn_mfma_f32_16x16x32_bf16(aP0[mi], b0, acc[mi][ci], 0, 0, 0);
        acc[mi][ci] = __builtin_amdgcn_mfma_f32_16x16x32_bf16(aP1[mi], b1, acc[mi][ci], 0, 0, 0);
      }
    }
  }
  if (ql == 0) {
    #pragma unroll
    for (int r = 0; r < 4; ++r) l_sh[rql + quad*4 + r] = lrow[r];
  }
  __syncthreads();
  #pragma unroll
  for (int mi = 0; mi < 2; ++mi)
    #pragma unroll
    for (int r = 0; r < 4; ++r) {
      int row = pvr + mi*16 + quad*4 + r;
      float inv = 1.f / l_sh[row];
      #pragma unroll
      for (int ci = 0; ci < 8; ++ci)
        Y[((long)(b*Nn) + q0 + row)*256 + pvc + ci*16 + ql] = __float2bfloat16(acc[mi][ci][r]*inv);
    }
}

// ---------------- wconv MFMA GEMM: out[b][o][n] = Ww @ Y^T, BN, +x
__global__ __launch_bounds__(256) void wconv_kernel(
    const bf16* __restrict__ Y, const float* __restrict__ Ww, const float* __restrict__ Wb,
    const float* __restrict__ gamma, const float* __restrict__ beta,
    const float* __restrict__ mean, const float* __restrict__ var,
    const float* __restrict__ x, float* __restrict__ out)
{
  __shared__ __align__(16) ushort As[128*40];
  __shared__ __align__(16) ushort Bs[128*40];
  __shared__ float ssc[128], ssh[128];
  const int t = threadIdx.x;
  const int n0 = blockIdx.x*128, o0 = blockIdx.y*128, b = blockIdx.z;
  const int lane = t & 63, w = t >> 6;
  const int ql = lane & 15, quad = lane >> 4;
  const int wm = (w & 1)*64, wn = (w >> 1)*64;
  const ushort* Yu = (const ushort*)Y;

  if (t < 128) {
    int o = o0 + t;
    float sc = gamma[o] * rsqrtf(var[o] + EPSf);
    ssc[t] = sc;
    ssh[t] = (Wb[o] - mean[o])*sc + beta[o];
  }

  f32x4 acc[4][4];
  #pragma unroll
  for (int i = 0; i < 4; ++i)
    #pragma unroll
    for (int j = 0; j < 4; ++j) acc[i][j] = (f32x4){0.f,0.f,0.f,0.f};

  for (int kc = 0; kc < 8; ++kc) {
    __syncthreads();
    #pragma unroll
    for (int i = 0; i < 4; ++i) {
      int idx = t + i*256; int r = idx >> 3, cq = idx & 7;
      float4 v = *(const float4*)(Ww + (o0 + r)*Cn + kc*32 + cq*4);
      uint lo = (uint)f2bu(v.x) | ((uint)f2bu(v.y) << 16);
      uint hi = (uint)f2bu(v.z) | ((uint)f2bu(v.w) << 16);
      *(uint2*)(As + r*40 + cq*4) = make_uint2(lo, hi);
    }
    #pragma unroll
    for (int i = 0; i < 2; ++i) {
      int idx = t + i*256; int r = idx >> 2, cq = idx & 3;
      *(uint4*)(Bs + r*40 + cq*8) =
          *(const uint4*)(Yu + ((long)(b*Nn) + n0 + r)*Cn + kc*32 + cq*8);
    }
    __syncthreads();
    short8 aF[4], bF[4];
    #pragma unroll
    for (int mi = 0; mi < 4; ++mi)
      aF[mi] = *(const short8*)(As + (wm + mi*16 + ql)*40 + quad*8);
    #pragma unroll
    for (int ni = 0; ni < 4; ++ni)
      bF[ni] = *(const short8*)(Bs + (wn + ni*16 + ql)*40 + quad*8);
    #pragma unroll
    for (int mi = 0; mi < 4; ++mi)
      #pragma unroll
      for (int ni = 0; ni < 4; ++ni)
        acc[mi][ni] = __builtin_amdgcn_mfma_f32_16x16x32_bf16(aF[mi], bF[ni], acc[mi][ni], 0, 0, 0);
  }
  #pragma unroll
  for (int mi = 0; mi < 4; ++mi)
    #pragma unroll
    for (int r = 0; r < 4; ++r) {
      int ol = wm + mi*16 + quad*4 + r;
      int o = o0 + ol;
      float sc = ssc[ol], sh = ssh[ol];
      #pragma unroll
      for (int ni = 0; ni < 4; ++ni) {
        int n = n0 + wn + ni*16 + ql;
        long gidx = ((long)(b*Cn + o))*Nn + n;
        out[gidx] = acc[mi][ni][r]*sc + sh + x[gidx];
      }
    }
}

extern "C" void kernel_launch(void* const* d_in, const int* in_sizes, int n_in,
                              void* d_out, int out_size, void* d_ws, size_t ws_size,
                              hipStream_t stream)
{
  const float* x       = (const float*)d_in[0];
  const float* g_w     = (const float*)d_in[1];
  const float* g_b     = (const float*)d_in[2];
  const float* theta_w = (const float*)d_in[3];
  const float* theta_b = (const float*)d_in[4];
  const float* phi_w   = (const float*)d_in[5];
  const float* phi_b   = (const float*)d_in[6];
  const float* W_w     = (const float*)d_in[7];
  const float* W_b     = (const float*)d_in[8];
  const float* bn_g    = (const float*)d_in[9];
  const float* bn_b    = (const float*)d_in[10];
  const float* bn_m    = (const float*)d_in[11];
  const float* bn_v    = (const float*)d_in[12];
  float* out = (float*)d_out;

  bf16* wsb = (bf16*)d_ws;
  bf16* xT    = wsb;                  // B*N*C = 8,388,608 (dead after gemm384)
  bf16* Y     = wsb;                  // alias xT
  bf16* Q     = wsb + 8388608;        // B*N*64  = 2,097,152
  bf16* K     = wsb + 10485760;       // B*M*64  =   524,288
  bf16* Vt    = wsb + 11010048;       // B*C*M   = 2,097,152
  bf16* Wcomb = wsb + 13107200;       // 384*256 =    98,304
  float* bcomb = (float*)(wsb + 13205504);  // 384 fp32

  transpose_kernel<<<dim3(64, 4, Bn), 256, 0, stream>>>(x, xT);
  wcomb_kernel<<<dim3(384), 256, 0, stream>>>(theta_w, theta_b, phi_w, phi_b, g_w, g_b, Wcomb, bcomb);
  gemm384_kernel<<<dim3(32, 3, Bn), 256, 0, stream>>>(xT, Wcomb, bcomb, Q, K, Vt);
  attn_kernel<<<dim3(64, Bn), 256, 0, stream>>>(Q, K, Vt, Y);
  wconv_kernel<<<dim3(32, 2, Bn), 256, 0, stream>>>(Y, W_w, W_b, bn_g, bn_b, bn_m, bn_v, x, out);
}